// Round 5
// baseline (1043.303 us; speedup 1.0000x reference)
//
#include <hip/hip_runtime.h>

typedef unsigned short u16;
typedef _Float16 f16;
typedef __attribute__((ext_vector_type(8))) _Float16 f16x8;
typedef __attribute__((ext_vector_type(2))) float f32x2;
typedef __attribute__((ext_vector_type(4))) float f32x4;

#define D 128
#define LDW 136  // padded LDS row (f16 elems); 2-way bank alias only (free)

// ---------------- fp32 -> fp16 convert (8 elems/thread) ----------------
__global__ __launch_bounds__(256) void k_convert(const float* __restrict__ in,
                                                 u16* __restrict__ out, int n8) {
  int i = blockIdx.x * 256 + threadIdx.x;
  if (i >= n8) return;
  const float4* ip = (const float4*)in;
  float4 a = ip[i * 2], b = ip[i * 2 + 1];
  f16x8 v = {(f16)a.x, (f16)a.y, (f16)a.z, (f16)a.w,
             (f16)b.x, (f16)b.y, (f16)b.z, (f16)b.w};
  *(f16x8*)(out + (size_t)i * 8) = v;
}

// ---------------- W (9 x 128 x 128 fp32) -> fp16 transposed [mat][n][k] -----
__global__ __launch_bounds__(256) void k_convW(const float* __restrict__ W,
                                               u16* __restrict__ Wt, int total) {
  int idx = blockIdx.x * 256 + threadIdx.x;
  if (idx >= total) return;
  int mat = idx >> 14;
  int k = (idx >> 7) & 127;
  int n = idx & 127;
  f16 v = (f16)W[idx];
  ((f16*)Wt)[(size_t)mat * 16384 + n * 128 + k] = v;
}

// ---------------- CSR build: count (all 3 etypes, one dispatch) -------------
__global__ __launch_bounds__(256) void k_count3(
    const int* __restrict__ fd, const int* __restrict__ cd,
    const int* __restrict__ cbd, int* __restrict__ cnt,
    int NU, int NI, int nf, int nc, int ncb) {
  int e = blockIdx.x * 256 + threadIdx.x;
  if (e < nf)
    atomicAdd(&cnt[fd[e]], 1);
  else if (e < nf + nc)
    atomicAdd(&cnt[NU + cd[e - nf]], 1);
  else if (e < nf + nc + ncb)
    atomicAdd(&cnt[NU + NI + cbd[e - nf - nc]], 1);
}

// ---------------- device-wide exclusive scan, 3 passes ----------------
__global__ __launch_bounds__(256) void k_scanA(const int* __restrict__ cnt,
                                               int* __restrict__ part, int n) {
  int t = threadIdx.x;
  int idx = blockIdx.x * 1024 + t * 4;
  int4 v = {0, 0, 0, 0};
  if (idx + 3 < n)
    v = *(const int4*)(cnt + idx);
  else {
    if (idx < n) v.x = cnt[idx];
    if (idx + 1 < n) v.y = cnt[idx + 1];
    if (idx + 2 < n) v.z = cnt[idx + 2];
    if (idx + 3 < n) v.w = cnt[idx + 3];
  }
  int s = v.x + v.y + v.z + v.w;
  for (int off = 1; off < 64; off <<= 1) s += __shfl_down(s, off, 64);
  __shared__ int ws[4];
  if ((t & 63) == 0) ws[t >> 6] = s;
  __syncthreads();
  if (t == 0) part[blockIdx.x] = ws[0] + ws[1] + ws[2] + ws[3];
}

__global__ __launch_bounds__(1024) void k_scanB(int* __restrict__ part, int n_part) {
  __shared__ int sh[1024];
  int t = threadIdx.x;
  int v = (t < n_part) ? part[t] : 0;
  sh[t] = v;
  __syncthreads();
  for (int off = 1; off < 1024; off <<= 1) {
    int u = (t >= off) ? sh[t - off] : 0;
    __syncthreads();
    sh[t] += u;
    __syncthreads();
  }
  if (t < n_part) part[t] = sh[t] - v;  // exclusive
}

__global__ __launch_bounds__(256) void k_scanC(const int* __restrict__ cnt,
                                               const int* __restrict__ part,
                                               int* __restrict__ rs,
                                               int n, int total) {
  int t = threadIdx.x;
  int idx = blockIdx.x * 1024 + t * 4;
  int4 v = {0, 0, 0, 0};
  if (idx + 3 < n)
    v = *(const int4*)(cnt + idx);
  else {
    if (idx < n) v.x = cnt[idx];
    if (idx + 1 < n) v.y = cnt[idx + 1];
    if (idx + 2 < n) v.z = cnt[idx + 2];
    if (idx + 3 < n) v.w = cnt[idx + 3];
  }
  int s = v.x + v.y + v.z + v.w;
  int inc = s;
  int lane = t & 63, w = t >> 6;
  for (int off = 1; off < 64; off <<= 1) {
    int u = __shfl_up(inc, off, 64);
    if (lane >= off) inc += u;
  }
  __shared__ int ws[4];
  if (lane == 63) ws[w] = inc;
  __syncthreads();
  int woff = 0;
  for (int i = 0; i < w; ++i) woff += ws[i];
  int ex = part[blockIdx.x] + woff + inc - s;
  int4 r;
  r.x = ex;
  r.y = ex + v.x;
  r.z = r.y + v.y;
  r.w = r.z + v.z;
  if (idx + 3 < n)
    *(int4*)(rs + idx) = r;
  else {
    if (idx < n) rs[idx] = r.x;
    if (idx + 1 < n) rs[idx + 1] = r.y;
    if (idx + 2 < n) rs[idx + 2] = r.z;
    if (idx + 3 < n) rs[idx + 3] = r.w;
  }
  if (blockIdx.x == 0 && t == 0) rs[n] = total;
}

// ---------------- CSR build: fill (all 3 etypes; cnt used as countdown) -----
__global__ __launch_bounds__(256) void k_fill3(
    const int* __restrict__ fs, const int* __restrict__ fd,
    const int* __restrict__ cs, const int* __restrict__ cd,
    const int* __restrict__ cbs, const int* __restrict__ cbd,
    const int* __restrict__ rs, int* __restrict__ cnt, int* __restrict__ csr,
    int NU, int NI, int nf, int nc, int ncb) {
  int e = blockIdx.x * 256 + threadIdx.x;
  int d, s;
  if (e < nf) {
    d = fd[e];
    s = fs[e];
  } else if (e < nf + nc) {
    d = NU + cd[e - nf];
    s = cs[e - nf];
  } else if (e < nf + nc + ncb) {
    d = NU + NI + cbd[e - nf - nc];
    s = cbs[e - nf - nc] + NU;  // item sources live at h_all + NU rows
  } else
    return;
  int p = atomicSub(&cnt[d], 1);  // old value in 1..deg
  csr[rs[d] + p - 1] = s;
}

// ---------------- gather + mean into LDS tile (128 rows) ----------------
// 4 waves; wave handles 32 nodes; 16 lanes per node, 4 nodes concurrent.
__device__ __forceinline__ void gather_lds(f16 (*Msh)[LDW],
    const u16* __restrict__ h_all, const int* __restrict__ csr,
    const int* __restrict__ rs_all, int gbase, int Mrows) {
  int tid = threadIdx.x;
  int wv = tid >> 6, lane = tid & 63, l16 = lane & 15, grp = lane >> 4;
  const char* hb = (const char*)h_all;
  unsigned loff = (unsigned)l16 * 16u;
#pragma unroll 1
  for (int it = 0; it < 8; ++it) {
    int nidx = wv * 32 + it * 4 + grp;
    bool valid = nidx < Mrows;
    int g = gbase + (valid ? nidx : 0);
    int e = rs_all[g];
    int en = valid ? rs_all[g + 1] : e;
    int deg = en - e;
    f32x2 ac0 = {0.f, 0.f}, ac1 = {0.f, 0.f}, ac2 = {0.f, 0.f}, ac3 = {0.f, 0.f};
    while (__any(e < en)) {
      bool a0 = e < en, a1 = e + 1 < en;
      int s0 = a0 ? csr[e] : 0;
      int s1 = a1 ? csr[e + 1] : 0;
      f16x8 v0 = {0, 0, 0, 0, 0, 0, 0, 0}, v1 = {0, 0, 0, 0, 0, 0, 0, 0};
      if (a0) v0 = *(const f16x8*)(hb + ((unsigned)s0 * 256u + loff));
      if (a1) v1 = *(const f16x8*)(hb + ((unsigned)s1 * 256u + loff));
      ac0 += (f32x2){(float)v0[0], (float)v0[1]};
      ac1 += (f32x2){(float)v0[2], (float)v0[3]};
      ac2 += (f32x2){(float)v0[4], (float)v0[5]};
      ac3 += (f32x2){(float)v0[6], (float)v0[7]};
      ac0 += (f32x2){(float)v1[0], (float)v1[1]};
      ac1 += (f32x2){(float)v1[2], (float)v1[3]};
      ac2 += (f32x2){(float)v1[4], (float)v1[5]};
      ac3 += (f32x2){(float)v1[6], (float)v1[7]};
      e += 2;
    }
    if (valid) {
      float inv = deg > 0 ? 1.0f / (float)deg : 0.f;
      f16x8 r = {(f16)(ac0[0] * inv), (f16)(ac0[1] * inv),
                 (f16)(ac1[0] * inv), (f16)(ac1[1] * inv),
                 (f16)(ac2[0] * inv), (f16)(ac2[1] * inv),
                 (f16)(ac3[0] * inv), (f16)(ac3[1] * inv)};
      *(f16x8*)&Msh[nidx][l16 * 8] = r;
    }
  }
}

// ---------------- MFMA pass: acc += Msh(128x128) @ W(128x128) ----------------
// W read straight from global (L2-hot, 32 KB reused by all blocks).
__device__ __forceinline__ void mfma_pass(f32x4 acc[2][8],
    const f16 (*Msh)[LDW], const u16* __restrict__ Wmat) {
  int tid = threadIdx.x, lane = tid & 63, wv = tid >> 6;
  int lr = lane & 15, lk = (lane >> 4) * 8;
  const f16* Wg = (const f16*)Wmat;
#pragma unroll
  for (int ks = 0; ks < 4; ++ks) {
    int k0 = ks * 32 + lk;
    f16x8 bf[8];
#pragma unroll
    for (int n = 0; n < 8; ++n)
      bf[n] = *(const f16x8*)(Wg + (n * 16 + lr) * D + k0);
#pragma unroll
    for (int rt = 0; rt < 2; ++rt) {
      f16x8 af = *(const f16x8*)&Msh[wv * 32 + rt * 16 + lr][k0];
#pragma unroll
      for (int n = 0; n < 8; ++n)
        acc[rt][n] = __builtin_amdgcn_mfma_f32_16x16x32_f16(af, bf[n], acc[rt][n], 0, 0, 0);
    }
  }
}

// ---------------- epilogue: bias masks + leaky + store ----------------
template <int NE, int OUTF32>
__device__ __forceinline__ void epilogue(f32x4 acc[2][8],
    const float* __restrict__ bA, const float* __restrict__ bB,
    const int* __restrict__ rsA, const int* __restrict__ rsB,
    u16* __restrict__ o16, float* __restrict__ o32, int Mrows) {
  int tid = threadIdx.x, lane = tid & 63, wv = tid >> 6;
  int lr = lane & 15;
  float bAr[8], bBr[8];
#pragma unroll
  for (int n = 0; n < 8; ++n) {
    bAr[n] = bA[n * 16 + lr];
    bBr[n] = (NE == 2) ? bB[n * 16 + lr] : 0.f;
  }
#pragma unroll
  for (int rt = 0; rt < 2; ++rt) {
    int rbase = wv * 32 + rt * 16 + (lane >> 4) * 4;
#pragma unroll
    for (int i = 0; i < 4; ++i) {
      int r = rbase + i;
      if (r < Mrows) {
        bool mAok = rsA[r + 1] > rsA[r];
        bool mBok = (NE == 2) && rsB[r + 1] > rsB[r];
#pragma unroll
        for (int n = 0; n < 8; ++n) {
          int col = n * 16 + lr;
          float v = acc[rt][n][i];
          if (mAok) v += bAr[n];
          if (mBok) v += bBr[n];
          v = v > 0.f ? v : 0.01f * v;
          if (OUTF32)
            o32[(size_t)r * D + col] = v;
          else
            ((f16*)o16)[(size_t)r * D + col] = (f16)v;
        }
      }
    }
  }
}

// ---------------- fused per-layer kernel: item blocks then user blocks ------
template <int OUTF32>
__global__ __launch_bounds__(256) void k_fused(
    const u16* __restrict__ hcur, const int* __restrict__ csr,
    const int* __restrict__ rs_all, const u16* __restrict__ Wl,
    const float* __restrict__ bl, u16* __restrict__ hnxt,
    float* __restrict__ out, int NU, int NI, int nbI) {
  __shared__ __align__(16) f16 Msh[128][LDW];
  f32x4 acc[2][8];
#pragma unroll
  for (int rt = 0; rt < 2; ++rt)
#pragma unroll
    for (int n = 0; n < 8; ++n) acc[rt][n] = (f32x4){0.f, 0.f, 0.f, 0.f};

  if ((int)blockIdx.x < nbI) {
    // items: hi_next = leaky(mean_clicks(hu) @ W1 + mask*b1)
    int m0 = blockIdx.x * 128;
    int Mr = min(128, NI - m0);
    gather_lds(Msh, hcur, csr, rs_all, NU + m0, Mr);
    __syncthreads();
    mfma_pass(acc, Msh, Wl + 16384);
    epilogue<1, OUTF32>(acc, bl + D, nullptr, rs_all + NU + m0, nullptr,
                        hnxt + (size_t)(NU + m0) * D,
                        out + (size_t)(NU + m0) * D, Mr);
  } else {
    // users: hu_next = leaky(mean_f(hu) @ W0 + mean_cb(hi) @ W2 + masked b)
    int m0 = (blockIdx.x - nbI) * 128;
    int Mr = min(128, NU - m0);
    gather_lds(Msh, hcur, csr, rs_all, m0, Mr);
    __syncthreads();
    mfma_pass(acc, Msh, Wl);
    __syncthreads();  // all waves done reading Msh before overwrite
    gather_lds(Msh, hcur, csr, rs_all, NU + NI + m0, Mr);
    __syncthreads();
    mfma_pass(acc, Msh, Wl + 2 * 16384);
    epilogue<2, OUTF32>(acc, bl, bl + 2 * D, rs_all + m0, rs_all + NU + NI + m0,
                        hnxt + (size_t)m0 * D, out + (size_t)m0 * D, Mr);
  }
}

extern "C" void kernel_launch(void* const* d_in, const int* in_sizes, int n_in,
                              void* d_out, int out_size, void* d_ws, size_t ws_size,
                              hipStream_t stream) {
  const float* h_user = (const float*)d_in[0];
  const float* h_item = (const float*)d_in[1];
  const float* W = (const float*)d_in[2];
  const float* bb = (const float*)d_in[3];
  const int* f_src = (const int*)d_in[4];
  const int* f_dst = (const int*)d_in[5];
  const int* c_src = (const int*)d_in[6];
  const int* c_dst = (const int*)d_in[7];
  const int* cb_src = (const int*)d_in[8];
  const int* cb_dst = (const int*)d_in[9];

  const int NU = in_sizes[0] / D;
  const int NI = in_sizes[1] / D;
  const int nEf = in_sizes[4], nEc = in_sizes[6], nEcb = in_sizes[8];
  const int N3 = NU + NI + NU;
  const int nE = nEf + nEc + nEcb;

  char* p = (char*)d_ws;
  auto alloc = [&](size_t bytes) {
    char* r = p;
    p += (bytes + 255) & ~(size_t)255;
    return r;
  };
  int* cnt_all = (int*)alloc((size_t)N3 * 4);
  int* rs_all = (int*)alloc((size_t)(N3 + 1) * 4);
  int* part = (int*)alloc(1024 * 4);
  u16* Wtg = (u16*)alloc((size_t)9 * 16384 * 2);
  int* csr_all = (int*)alloc((size_t)nE * 4);
  u16* hA = (u16*)alloc((size_t)(NU + NI) * D * 2);  // [hu | hi] ping
  u16* hB = (u16*)alloc((size_t)(NU + NI) * D * 2);  // pong
  (void)ws_size;  // ~113 MB total

  hipMemsetAsync(cnt_all, 0, (size_t)N3 * 4, stream);

  k_convert<<<(NU * D / 8 + 255) / 256, 256, 0, stream>>>(h_user, hA, NU * D / 8);
  k_convert<<<(NI * D / 8 + 255) / 256, 256, 0, stream>>>(h_item, hA + (size_t)NU * D,
                                                          NI * D / 8);
  k_convW<<<(9 * 16384 + 255) / 256, 256, 0, stream>>>(W, Wtg, 9 * 16384);

  k_count3<<<(nE + 255) / 256, 256, 0, stream>>>(f_dst, c_dst, cb_dst, cnt_all,
                                                 NU, NI, nEf, nEc, nEcb);

  int n_part = (N3 + 1023) / 1024;
  k_scanA<<<n_part, 256, 0, stream>>>(cnt_all, part, N3);
  k_scanB<<<1, 1024, 0, stream>>>(part, n_part);
  k_scanC<<<n_part, 256, 0, stream>>>(cnt_all, part, rs_all, N3, nE);

  k_fill3<<<(nE + 255) / 256, 256, 0, stream>>>(f_src, f_dst, c_src, c_dst,
                                                cb_src, cb_dst, rs_all, cnt_all,
                                                csr_all, NU, NI, nEf, nEc, nEcb);

  int nbI = (NI + 127) / 128;
  int nbU = (NU + 127) / 128;

  u16* hcur = hA;
  u16* hnxt = hB;
  for (int l = 0; l < 3; ++l) {
    const u16* Wl = Wtg + (size_t)l * 3 * 16384;
    const float* bl = bb + (size_t)l * 3 * D;
    if (l < 2)
      k_fused<0><<<nbI + nbU, 256, 0, stream>>>(hcur, csr_all, rs_all, Wl, bl,
                                                hnxt, (float*)d_out, NU, NI, nbI);
    else
      k_fused<1><<<nbI + nbU, 256, 0, stream>>>(hcur, csr_all, rs_all, Wl, bl,
                                                hnxt, (float*)d_out, NU, NI, nbI);
    u16* t = hcur;
    hcur = hnxt;
    hnxt = t;
  }
}

// Round 6
// 625.514 us; speedup vs baseline: 1.6679x; 1.6679x over previous
//
#include <hip/hip_runtime.h>

typedef unsigned short u16;
typedef _Float16 f16;
typedef __attribute__((ext_vector_type(8))) _Float16 f16x8;
typedef __attribute__((ext_vector_type(4))) float f32x4;

#define D 128

// ---------------- fp32 -> fp16 convert (8 elems/thread) ----------------
__global__ __launch_bounds__(256) void k_convert(const float* __restrict__ in,
                                                 u16* __restrict__ out, int n8) {
  int i = blockIdx.x * 256 + threadIdx.x;
  if (i >= n8) return;
  const float4* ip = (const float4*)in;
  float4 a = ip[i * 2], b = ip[i * 2 + 1];
  f16x8 v = {(f16)a.x, (f16)a.y, (f16)a.z, (f16)a.w,
             (f16)b.x, (f16)b.y, (f16)b.z, (f16)b.w};
  *(f16x8*)(out + (size_t)i * 8) = v;
}

// ---------------- W (9 x 128 x 128 fp32) -> fp16 transposed [mat][n][k] -----
__global__ __launch_bounds__(256) void k_convW(const float* __restrict__ W,
                                               u16* __restrict__ Wt, int total) {
  int idx = blockIdx.x * 256 + threadIdx.x;
  if (idx >= total) return;
  int mat = idx >> 14;
  int k = (idx >> 7) & 127;
  int n = idx & 127;
  f16 v = (f16)W[idx];
  ((f16*)Wt)[(size_t)mat * 16384 + n * 128 + k] = v;
}

// ---------------- CSR build: count (all 3 etypes, one dispatch) -------------
__global__ __launch_bounds__(256) void k_count3(
    const int* __restrict__ fd, const int* __restrict__ cd,
    const int* __restrict__ cbd, int* __restrict__ cnt,
    int NU, int NI, int nf, int nc, int ncb) {
  int e = blockIdx.x * 256 + threadIdx.x;
  if (e < nf)
    atomicAdd(&cnt[fd[e]], 1);
  else if (e < nf + nc)
    atomicAdd(&cnt[NU + cd[e - nf]], 1);
  else if (e < nf + nc + ncb)
    atomicAdd(&cnt[NU + NI + cbd[e - nf - nc]], 1);
}

// ---------------- device-wide exclusive scan, 3 passes ----------------
__global__ __launch_bounds__(256) void k_scanA(const int* __restrict__ cnt,
                                               int* __restrict__ part, int n) {
  int t = threadIdx.x;
  int idx = blockIdx.x * 1024 + t * 4;
  int4 v = {0, 0, 0, 0};
  if (idx + 3 < n)
    v = *(const int4*)(cnt + idx);
  else {
    if (idx < n) v.x = cnt[idx];
    if (idx + 1 < n) v.y = cnt[idx + 1];
    if (idx + 2 < n) v.z = cnt[idx + 2];
    if (idx + 3 < n) v.w = cnt[idx + 3];
  }
  int s = v.x + v.y + v.z + v.w;
  for (int off = 1; off < 64; off <<= 1) s += __shfl_down(s, off, 64);
  __shared__ int ws[4];
  if ((t & 63) == 0) ws[t >> 6] = s;
  __syncthreads();
  if (t == 0) part[blockIdx.x] = ws[0] + ws[1] + ws[2] + ws[3];
}

__global__ __launch_bounds__(1024) void k_scanB(int* __restrict__ part, int n_part) {
  __shared__ int sh[1024];
  int t = threadIdx.x;
  int v = (t < n_part) ? part[t] : 0;
  sh[t] = v;
  __syncthreads();
  for (int off = 1; off < 1024; off <<= 1) {
    int u = (t >= off) ? sh[t - off] : 0;
    __syncthreads();
    sh[t] += u;
    __syncthreads();
  }
  if (t < n_part) part[t] = sh[t] - v;  // exclusive
}

__global__ __launch_bounds__(256) void k_scanC(const int* __restrict__ cnt,
                                               const int* __restrict__ part,
                                               int* __restrict__ rs,
                                               int n, int total) {
  int t = threadIdx.x;
  int idx = blockIdx.x * 1024 + t * 4;
  int4 v = {0, 0, 0, 0};
  if (idx + 3 < n)
    v = *(const int4*)(cnt + idx);
  else {
    if (idx < n) v.x = cnt[idx];
    if (idx + 1 < n) v.y = cnt[idx + 1];
    if (idx + 2 < n) v.z = cnt[idx + 2];
    if (idx + 3 < n) v.w = cnt[idx + 3];
  }
  int s = v.x + v.y + v.z + v.w;
  int inc = s;
  int lane = t & 63, w = t >> 6;
  for (int off = 1; off < 64; off <<= 1) {
    int u = __shfl_up(inc, off, 64);
    if (lane >= off) inc += u;
  }
  __shared__ int ws[4];
  if (lane == 63) ws[w] = inc;
  __syncthreads();
  int woff = 0;
  for (int i = 0; i < w; ++i) woff += ws[i];
  int ex = part[blockIdx.x] + woff + inc - s;
  int4 r;
  r.x = ex;
  r.y = ex + v.x;
  r.z = r.y + v.y;
  r.w = r.z + v.z;
  if (idx + 3 < n)
    *(int4*)(rs + idx) = r;
  else {
    if (idx < n) rs[idx] = r.x;
    if (idx + 1 < n) rs[idx + 1] = r.y;
    if (idx + 2 < n) rs[idx + 2] = r.z;
    if (idx + 3 < n) rs[idx + 3] = r.w;
  }
  if (blockIdx.x == 0 && t == 0) rs[n] = total;
}

// ---------------- CSR build: fill (all 3 etypes; cnt used as countdown) -----
__global__ __launch_bounds__(256) void k_fill3(
    const int* __restrict__ fs, const int* __restrict__ fd,
    const int* __restrict__ cs, const int* __restrict__ cd,
    const int* __restrict__ cbs, const int* __restrict__ cbd,
    const int* __restrict__ rs, int* __restrict__ cnt, int* __restrict__ csr,
    int NU, int NI, int nf, int nc, int ncb) {
  int e = blockIdx.x * 256 + threadIdx.x;
  int d, s;
  if (e < nf) {
    d = fd[e];
    s = fs[e];
  } else if (e < nf + nc) {
    d = NU + cd[e - nf];
    s = cs[e - nf];
  } else if (e < nf + nc + ncb) {
    d = NU + NI + cbd[e - nf - nc];
    s = cbs[e - nf - nc] + NU;  // item sources live at h_all + NU rows
  } else
    return;
  int p = atomicSub(&cnt[d], 1);  // old value in 1..deg
  csr[rs[d] + p - 1] = s;
}

// ---- mean aggregation: 4 nodes/wave, 16 lanes/node, f16 accum, 4-edge MLP --
__global__ __launch_bounds__(256) void k_agg3(
    const u16* __restrict__ h_all, const int* __restrict__ csr,
    const int* __restrict__ rs, u16* __restrict__ M_all, int N3) {
  int wave = (blockIdx.x * 256 + threadIdx.x) >> 6;
  int lane = threadIdx.x & 63;
  int l16 = lane & 15;
  int w = wave * 4 + (lane >> 4);
  bool valid = w < N3;
  int wc = valid ? w : 0;
  int e = rs[wc];
  int en = valid ? rs[wc + 1] : 0;
  int deg = en - e;
  f16x8 acc0 = {0, 0, 0, 0, 0, 0, 0, 0};
  f16x8 acc1 = {0, 0, 0, 0, 0, 0, 0, 0};
  const char* hb = (const char*)h_all;
  unsigned loff = (unsigned)l16 * 16u;

  while (__any(e < en)) {
    bool a0 = e < en, a1 = e + 1 < en, a2 = e + 2 < en, a3 = e + 3 < en;
    int s0 = a0 ? csr[e] : 0;
    int s1 = a1 ? csr[e + 1] : 0;
    int s2 = a2 ? csr[e + 2] : 0;
    int s3 = a3 ? csr[e + 3] : 0;
    f16x8 v0 = {0, 0, 0, 0, 0, 0, 0, 0}, v1 = {0, 0, 0, 0, 0, 0, 0, 0};
    f16x8 v2 = {0, 0, 0, 0, 0, 0, 0, 0}, v3 = {0, 0, 0, 0, 0, 0, 0, 0};
    if (a0) v0 = *(const f16x8*)(hb + ((unsigned)s0 * 256u + loff));
    if (a1) v1 = *(const f16x8*)(hb + ((unsigned)s1 * 256u + loff));
    if (a2) v2 = *(const f16x8*)(hb + ((unsigned)s2 * 256u + loff));
    if (a3) v3 = *(const f16x8*)(hb + ((unsigned)s3 * 256u + loff));
    acc0 += v0;
    acc1 += v1;
    acc0 += v2;
    acc1 += v3;
    e += 4;
  }

  if (valid) {
    float invf = deg > 0 ? 1.0f / (float)deg : 0.f;
    f16 hinv = (f16)invf;
    f16x8 t = acc0 + acc1;
    f16x8 r = t * hinv;
    *(f16x8*)((char*)M_all + ((unsigned)wc * 256u + loff)) = r;
  }
}

// ---------------- GEMM body: no LDS, W streamed from global/L2 ----------------
template <int NE, int OUTF32>
__device__ __forceinline__ void gemm_body(
    const u16* __restrict__ mA, const u16* __restrict__ mBp,
    const u16* __restrict__ wtA, const u16* __restrict__ wtB,  // fp16 [n][k]
    const float* __restrict__ bA, const float* __restrict__ bB,
    const int* __restrict__ rsA, const int* __restrict__ rsB,
    u16* __restrict__ o16, float* __restrict__ o32, int M, int blk) {
  int tid = threadIdx.x, lane = tid & 63, w = tid >> 6;
  int lr = lane & 15;
  int lk = (lane >> 4) * 8;
  long row0 = (long)blk * 128 + w * 32;

  f32x4 acc[2][8];
#pragma unroll
  for (int rt = 0; rt < 2; rt++)
#pragma unroll
    for (int n = 0; n < 8; n++) acc[rt][n] = (f32x4){0.f, 0.f, 0.f, 0.f};

#pragma unroll
  for (int e = 0; e < NE; ++e) {
    const f16* mm = (const f16*)((e == 0) ? mA : mBp);
    const f16* Wg = (const f16*)((e == 0) ? wtA : wtB);
#pragma unroll
    for (int ks = 0; ks < 4; ++ks) {
      int k0 = ks * 32 + lk;
      f16x8 bf[8];
#pragma unroll
      for (int n = 0; n < 8; n++) bf[n] = *(const f16x8*)(Wg + (n * 16 + lr) * D + k0);
#pragma unroll
      for (int rt = 0; rt < 2; rt++) {
        long r = row0 + rt * 16 + lr;
        if (r >= M) r = M - 1;  // clamped load; store guarded
        f16x8 af = *(const f16x8*)(mm + r * D + k0);
#pragma unroll
        for (int n = 0; n < 8; n++)
          acc[rt][n] = __builtin_amdgcn_mfma_f32_16x16x32_f16(af, bf[n], acc[rt][n], 0, 0, 0);
      }
    }
  }

  float bAr[8], bBr[8];
#pragma unroll
  for (int n = 0; n < 8; n++) {
    bAr[n] = bA[n * 16 + lr];
    bBr[n] = (NE == 2) ? bB[n * 16 + lr] : 0.f;
  }

#pragma unroll
  for (int rt = 0; rt < 2; rt++) {
    long rbase = row0 + rt * 16 + (lane >> 4) * 4;
#pragma unroll
    for (int i = 0; i < 4; i++) {
      long r = rbase + i;
      if (r < M) {
        bool mAok = rsA[r + 1] > rsA[r];
        bool mBok = (NE == 2) && (rsB[r + 1] > rsB[r]);
#pragma unroll
        for (int n = 0; n < 8; n++) {
          int col = n * 16 + lr;
          float v = acc[rt][n][i];
          if (mAok) v += bAr[n];
          if (mBok) v += bBr[n];
          v = v > 0.f ? v : 0.01f * v;
          if (OUTF32)
            o32[r * D + col] = v;
          else
            ((f16*)o16)[r * D + col] = (f16)v;
        }
      }
    }
  }
}

// ---------------- fused per-layer GEMM: item blocks + user blocks ----------
template <int OUTF32>
__global__ __launch_bounds__(256) void k_gemm2(
    const u16* __restrict__ M_all, const u16* __restrict__ Wl,
    const float* __restrict__ bl, const int* __restrict__ rs_all,
    u16* __restrict__ h_all, float* __restrict__ out,
    int NU, int NI, int nbI) {
  if ((int)blockIdx.x < nbI) {
    // items: hi_next = leaky(Mc @ W1 + mask*b1)
    gemm_body<1, OUTF32>(M_all + (size_t)NU * D, nullptr,
                         Wl + 16384, nullptr,
                         bl + D, nullptr,
                         rs_all + NU, nullptr,
                         h_all + (size_t)NU * D, out + (size_t)NU * D, NI,
                         blockIdx.x);
  } else {
    // users: hu_next = leaky(Mf @ W0 + Mcb @ W2 + masked biases)
    gemm_body<2, OUTF32>(M_all, M_all + (size_t)(NU + NI) * D,
                         Wl, Wl + 2 * 16384,
                         bl, bl + 2 * D,
                         rs_all, rs_all + NU + NI,
                         h_all, out, NU, blockIdx.x - nbI);
  }
}

extern "C" void kernel_launch(void* const* d_in, const int* in_sizes, int n_in,
                              void* d_out, int out_size, void* d_ws, size_t ws_size,
                              hipStream_t stream) {
  const float* h_user = (const float*)d_in[0];
  const float* h_item = (const float*)d_in[1];
  const float* W = (const float*)d_in[2];
  const float* bb = (const float*)d_in[3];
  const int* f_src = (const int*)d_in[4];
  const int* f_dst = (const int*)d_in[5];
  const int* c_src = (const int*)d_in[6];
  const int* c_dst = (const int*)d_in[7];
  const int* cb_src = (const int*)d_in[8];
  const int* cb_dst = (const int*)d_in[9];

  const int NU = in_sizes[0] / D;
  const int NI = in_sizes[1] / D;
  const int nEf = in_sizes[4], nEc = in_sizes[6], nEcb = in_sizes[8];
  const int N3 = NU + NI + NU;
  const int nE = nEf + nEc + nEcb;

  char* p = (char*)d_ws;
  auto alloc = [&](size_t bytes) {
    char* r = p;
    p += (bytes + 255) & ~(size_t)255;
    return r;
  };
  int* cnt_all = (int*)alloc((size_t)N3 * 4);
  int* rs_all = (int*)alloc((size_t)(N3 + 1) * 4);
  int* part = (int*)alloc(1024 * 4);
  u16* Wtg = (u16*)alloc((size_t)9 * 16384 * 2);
  int* csr_all = (int*)alloc((size_t)nE * 4);
  u16* h_all = (u16*)alloc((size_t)(NU + NI) * D * 2);  // [hu | hi]
  u16* M_all = (u16*)alloc((size_t)N3 * D * 2);         // [Mf | Mc | Mcb]
  (void)ws_size;  // ~138 MB total (<= R3's proven usage)

  hipMemsetAsync(cnt_all, 0, (size_t)N3 * 4, stream);

  k_convert<<<(NU * D / 8 + 255) / 256, 256, 0, stream>>>(h_user, h_all, NU * D / 8);
  k_convert<<<(NI * D / 8 + 255) / 256, 256, 0, stream>>>(h_item, h_all + (size_t)NU * D,
                                                          NI * D / 8);
  k_convW<<<(9 * 16384 + 255) / 256, 256, 0, stream>>>(W, Wtg, 9 * 16384);

  k_count3<<<(nE + 255) / 256, 256, 0, stream>>>(f_dst, c_dst, cb_dst, cnt_all,
                                                 NU, NI, nEf, nEc, nEcb);

  int n_part = (N3 + 1023) / 1024;
  k_scanA<<<n_part, 256, 0, stream>>>(cnt_all, part, N3);
  k_scanB<<<1, 1024, 0, stream>>>(part, n_part);
  k_scanC<<<n_part, 256, 0, stream>>>(cnt_all, part, rs_all, N3, nE);

  k_fill3<<<(nE + 255) / 256, 256, 0, stream>>>(f_src, f_dst, c_src, c_dst,
                                                cb_src, cb_dst, rs_all, cnt_all,
                                                csr_all, NU, NI, nEf, nEc, nEcb);

  int nbI = (NI + 127) / 128;
  int nbU = (NU + 127) / 128;
  int agg_blocks = ((N3 + 3) / 4 + 3) / 4;

  for (int l = 0; l < 3; ++l) {
    const u16* Wl = Wtg + (size_t)l * 3 * 16384;
    const float* bl = bb + (size_t)l * 3 * D;

    k_agg3<<<agg_blocks, 256, 0, stream>>>(h_all, csr_all, rs_all, M_all, N3);

    if (l < 2)
      k_gemm2<0><<<nbI + nbU, 256, 0, stream>>>(M_all, Wl, bl, rs_all, h_all,
                                                (float*)d_out, NU, NI, nbI);
    else
      k_gemm2<1><<<nbI + nbU, 256, 0, stream>>>(M_all, Wl, bl, rs_all, h_all,
                                                (float*)d_out, NU, NI, nbI);
  }
}

// Round 7
// 577.681 us; speedup vs baseline: 1.8060x; 1.0828x over previous
//
#include <hip/hip_runtime.h>

typedef unsigned short u16;
typedef _Float16 f16;
typedef __attribute__((ext_vector_type(8))) _Float16 f16x8;
typedef __attribute__((ext_vector_type(4))) float f32x4;

#define D 128

// ---------------- fp32 -> fp16 convert (8 elems/thread) ----------------
__global__ __launch_bounds__(256) void k_convert(const float* __restrict__ in,
                                                 u16* __restrict__ out, int n8) {
  int i = blockIdx.x * 256 + threadIdx.x;
  if (i >= n8) return;
  const float4* ip = (const float4*)in;
  float4 a = ip[i * 2], b = ip[i * 2 + 1];
  f16x8 v = {(f16)a.x, (f16)a.y, (f16)a.z, (f16)a.w,
             (f16)b.x, (f16)b.y, (f16)b.z, (f16)b.w};
  *(f16x8*)(out + (size_t)i * 8) = v;
}

// ---------------- W (9 x 128 x 128 fp32) -> fp16 transposed [mat][n][k] -----
__global__ __launch_bounds__(256) void k_convW(const float* __restrict__ W,
                                               u16* __restrict__ Wt, int total) {
  int idx = blockIdx.x * 256 + threadIdx.x;
  if (idx >= total) return;
  int mat = idx >> 14;
  int k = (idx >> 7) & 127;
  int n = idx & 127;
  f16 v = (f16)W[idx];
  ((f16*)Wt)[(size_t)mat * 16384 + n * 128 + k] = v;
}

// ------- CSR build pass 1: count (line-padded) + record slot per edge -------
__global__ __launch_bounds__(256) void k_countpos(
    const int* __restrict__ fd, const int* __restrict__ cd,
    const int* __restrict__ cbd, int* __restrict__ cnt, u16* __restrict__ pos,
    int NU, int NI, int nf, int nc, int ncb, int S) {
  int e = blockIdx.x * 256 + threadIdx.x;
  int d;
  if (e < nf)
    d = fd[e];
  else if (e < nf + nc)
    d = NU + cd[e - nf];
  else if (e < nf + nc + ncb)
    d = NU + NI + cbd[e - nf - nc];
  else
    return;
  int p = atomicAdd(&cnt[d * S], 1);
  pos[e] = (u16)p;
}

// ---------------- device-wide exclusive scan over strided counters ----------
__global__ __launch_bounds__(256) void k_scanA(const int* __restrict__ cnt,
                                               int* __restrict__ part, int n, int S) {
  int t = threadIdx.x;
  int idx = blockIdx.x * 1024 + t * 4;
  int s = 0;
#pragma unroll
  for (int j = 0; j < 4; ++j)
    if (idx + j < n) s += cnt[(idx + j) * S];
  for (int off = 1; off < 64; off <<= 1) s += __shfl_down(s, off, 64);
  __shared__ int ws[4];
  if ((t & 63) == 0) ws[t >> 6] = s;
  __syncthreads();
  if (t == 0) part[blockIdx.x] = ws[0] + ws[1] + ws[2] + ws[3];
}

__global__ __launch_bounds__(1024) void k_scanB(int* __restrict__ part, int n_part) {
  __shared__ int sh[1024];
  int t = threadIdx.x;
  int v = (t < n_part) ? part[t] : 0;
  sh[t] = v;
  __syncthreads();
  for (int off = 1; off < 1024; off <<= 1) {
    int u = (t >= off) ? sh[t - off] : 0;
    __syncthreads();
    sh[t] += u;
    __syncthreads();
  }
  if (t < n_part) part[t] = sh[t] - v;  // exclusive
}

__global__ __launch_bounds__(256) void k_scanC(const int* __restrict__ cnt,
                                               const int* __restrict__ part,
                                               int* __restrict__ rs,
                                               int n, int total, int S) {
  int t = threadIdx.x;
  int idx = blockIdx.x * 1024 + t * 4;
  int v0 = 0, v1 = 0, v2 = 0, v3 = 0;
  if (idx < n) v0 = cnt[idx * S];
  if (idx + 1 < n) v1 = cnt[(idx + 1) * S];
  if (idx + 2 < n) v2 = cnt[(idx + 2) * S];
  if (idx + 3 < n) v3 = cnt[(idx + 3) * S];
  int s = v0 + v1 + v2 + v3;
  int inc = s;
  int lane = t & 63, w = t >> 6;
  for (int off = 1; off < 64; off <<= 1) {
    int u = __shfl_up(inc, off, 64);
    if (lane >= off) inc += u;
  }
  __shared__ int ws[4];
  if (lane == 63) ws[w] = inc;
  __syncthreads();
  int woff = 0;
  for (int i = 0; i < w; ++i) woff += ws[i];
  int ex = part[blockIdx.x] + woff + inc - s;
  int4 r;
  r.x = ex;
  r.y = ex + v0;
  r.z = r.y + v1;
  r.w = r.z + v2;
  if (idx + 3 < n)
    *(int4*)(rs + idx) = r;
  else {
    if (idx < n) rs[idx] = r.x;
    if (idx + 1 < n) rs[idx + 1] = r.y;
    if (idx + 2 < n) rs[idx + 2] = r.z;
    if (idx + 3 < n) rs[idx + 3] = r.w;
  }
  if (blockIdx.x == 0 && t == 0) rs[n] = total;
}

// ------- CSR build pass 2: atomic-free scatter using recorded slots ---------
__global__ __launch_bounds__(256) void k_fillpos(
    const int* __restrict__ fs, const int* __restrict__ fd,
    const int* __restrict__ cs, const int* __restrict__ cd,
    const int* __restrict__ cbs, const int* __restrict__ cbd,
    const int* __restrict__ rs, const u16* __restrict__ pos,
    int* __restrict__ csr, int NU, int NI, int nf, int nc, int ncb) {
  int e = blockIdx.x * 256 + threadIdx.x;
  int d, s;
  if (e < nf) {
    d = fd[e];
    s = fs[e];
  } else if (e < nf + nc) {
    d = NU + cd[e - nf];
    s = cs[e - nf];
  } else if (e < nf + nc + ncb) {
    d = NU + NI + cbd[e - nf - nc];
    s = cbs[e - nf - nc] + NU;  // item sources live at h_all + NU rows
  } else
    return;
  csr[rs[d] + (int)pos[e]] = s;
}

// ---- mean aggregation: 4 nodes/wave, 16 lanes/node, f16 accum, 4-edge MLP --
__global__ __launch_bounds__(256) void k_agg3(
    const u16* __restrict__ h_all, const int* __restrict__ csr,
    const int* __restrict__ rs, u16* __restrict__ M_all, int N3) {
  int wave = (blockIdx.x * 256 + threadIdx.x) >> 6;
  int lane = threadIdx.x & 63;
  int l16 = lane & 15;
  int w = wave * 4 + (lane >> 4);
  bool valid = w < N3;
  int wc = valid ? w : 0;
  int e = rs[wc];
  int en = valid ? rs[wc + 1] : 0;
  int deg = en - e;
  f16x8 acc0 = {0, 0, 0, 0, 0, 0, 0, 0};
  f16x8 acc1 = {0, 0, 0, 0, 0, 0, 0, 0};
  const char* hb = (const char*)h_all;
  unsigned loff = (unsigned)l16 * 16u;

  while (__any(e < en)) {
    bool a0 = e < en, a1 = e + 1 < en, a2 = e + 2 < en, a3 = e + 3 < en;
    int s0 = a0 ? csr[e] : 0;
    int s1 = a1 ? csr[e + 1] : 0;
    int s2 = a2 ? csr[e + 2] : 0;
    int s3 = a3 ? csr[e + 3] : 0;
    f16x8 v0 = {0, 0, 0, 0, 0, 0, 0, 0}, v1 = {0, 0, 0, 0, 0, 0, 0, 0};
    f16x8 v2 = {0, 0, 0, 0, 0, 0, 0, 0}, v3 = {0, 0, 0, 0, 0, 0, 0, 0};
    if (a0) v0 = *(const f16x8*)(hb + ((unsigned)s0 * 256u + loff));
    if (a1) v1 = *(const f16x8*)(hb + ((unsigned)s1 * 256u + loff));
    if (a2) v2 = *(const f16x8*)(hb + ((unsigned)s2 * 256u + loff));
    if (a3) v3 = *(const f16x8*)(hb + ((unsigned)s3 * 256u + loff));
    acc0 += v0;
    acc1 += v1;
    acc0 += v2;
    acc1 += v3;
    e += 4;
  }

  if (valid) {
    float invf = deg > 0 ? 1.0f / (float)deg : 0.f;
    f16 hinv = (f16)invf;
    f16x8 t = acc0 + acc1;
    f16x8 r = t * hinv;
    *(f16x8*)((char*)M_all + ((unsigned)wc * 256u + loff)) = r;
  }
}

// ---------------- GEMM body: no LDS, W streamed from global/L2 ----------------
template <int NE, int OUTF32>
__device__ __forceinline__ void gemm_body(
    const u16* __restrict__ mA, const u16* __restrict__ mBp,
    const u16* __restrict__ wtA, const u16* __restrict__ wtB,  // fp16 [n][k]
    const float* __restrict__ bA, const float* __restrict__ bB,
    const int* __restrict__ rsA, const int* __restrict__ rsB,
    u16* __restrict__ o16, float* __restrict__ o32, int M, int blk) {
  int tid = threadIdx.x, lane = tid & 63, w = tid >> 6;
  int lr = lane & 15;
  int lk = (lane >> 4) * 8;
  long row0 = (long)blk * 128 + w * 32;

  f32x4 acc[2][8];
#pragma unroll
  for (int rt = 0; rt < 2; rt++)
#pragma unroll
    for (int n = 0; n < 8; n++) acc[rt][n] = (f32x4){0.f, 0.f, 0.f, 0.f};

#pragma unroll
  for (int e = 0; e < NE; ++e) {
    const f16* mm = (const f16*)((e == 0) ? mA : mBp);
    const f16* Wg = (const f16*)((e == 0) ? wtA : wtB);
#pragma unroll
    for (int ks = 0; ks < 4; ++ks) {
      int k0 = ks * 32 + lk;
      f16x8 bf[8];
#pragma unroll
      for (int n = 0; n < 8; n++) bf[n] = *(const f16x8*)(Wg + (n * 16 + lr) * D + k0);
#pragma unroll
      for (int rt = 0; rt < 2; rt++) {
        long r = row0 + rt * 16 + lr;
        if (r >= M) r = M - 1;  // clamped load; store guarded
        f16x8 af = *(const f16x8*)(mm + r * D + k0);
#pragma unroll
        for (int n = 0; n < 8; n++)
          acc[rt][n] = __builtin_amdgcn_mfma_f32_16x16x32_f16(af, bf[n], acc[rt][n], 0, 0, 0);
      }
    }
  }

  float bAr[8], bBr[8];
#pragma unroll
  for (int n = 0; n < 8; n++) {
    bAr[n] = bA[n * 16 + lr];
    bBr[n] = (NE == 2) ? bB[n * 16 + lr] : 0.f;
  }

#pragma unroll
  for (int rt = 0; rt < 2; rt++) {
    long rbase = row0 + rt * 16 + (lane >> 4) * 4;
#pragma unroll
    for (int i = 0; i < 4; i++) {
      long r = rbase + i;
      if (r < M) {
        bool mAok = rsA[r + 1] > rsA[r];
        bool mBok = (NE == 2) && (rsB[r + 1] > rsB[r]);
#pragma unroll
        for (int n = 0; n < 8; n++) {
          int col = n * 16 + lr;
          float v = acc[rt][n][i];
          if (mAok) v += bAr[n];
          if (mBok) v += bBr[n];
          v = v > 0.f ? v : 0.01f * v;
          if (OUTF32)
            o32[r * D + col] = v;
          else
            ((f16*)o16)[r * D + col] = (f16)v;
        }
      }
    }
  }
}

// ---------------- fused per-layer GEMM: item blocks + user blocks ----------
template <int OUTF32>
__global__ __launch_bounds__(256) void k_gemm2(
    const u16* __restrict__ M_all, const u16* __restrict__ Wl,
    const float* __restrict__ bl, const int* __restrict__ rs_all,
    u16* __restrict__ h_all, float* __restrict__ out,
    int NU, int NI, int nbI) {
  if ((int)blockIdx.x < nbI) {
    // items: hi_next = leaky(Mc @ W1 + mask*b1)
    gemm_body<1, OUTF32>(M_all + (size_t)NU * D, nullptr,
                         Wl + 16384, nullptr,
                         bl + D, nullptr,
                         rs_all + NU, nullptr,
                         h_all + (size_t)NU * D, out + (size_t)NU * D, NI,
                         blockIdx.x);
  } else {
    // users: hu_next = leaky(Mf @ W0 + Mcb @ W2 + masked biases)
    gemm_body<2, OUTF32>(M_all, M_all + (size_t)(NU + NI) * D,
                         Wl, Wl + 2 * 16384,
                         bl, bl + 2 * D,
                         rs_all, rs_all + NU + NI,
                         h_all, out, NU, blockIdx.x - nbI);
  }
}

extern "C" void kernel_launch(void* const* d_in, const int* in_sizes, int n_in,
                              void* d_out, int out_size, void* d_ws, size_t ws_size,
                              hipStream_t stream) {
  const float* h_user = (const float*)d_in[0];
  const float* h_item = (const float*)d_in[1];
  const float* W = (const float*)d_in[2];
  const float* bb = (const float*)d_in[3];
  const int* f_src = (const int*)d_in[4];
  const int* f_dst = (const int*)d_in[5];
  const int* c_src = (const int*)d_in[6];
  const int* c_dst = (const int*)d_in[7];
  const int* cb_src = (const int*)d_in[8];
  const int* cb_dst = (const int*)d_in[9];

  const int NU = in_sizes[0] / D;
  const int NI = in_sizes[1] / D;
  const int nEf = in_sizes[4], nEc = in_sizes[6], nEcb = in_sizes[8];
  const int N3 = NU + NI + NU;
  const int nE = nEf + nEc + nEcb;

  // decide counter padding stride by available workspace
  size_t fixed = (size_t)(N3 + 1) * 4 + 1024 * 4 + (size_t)9 * 16384 * 2 +
                 (size_t)nE * 4 + (size_t)nE * 2 +
                 (size_t)(NU + NI) * D * 2 + (size_t)N3 * D * 2 + 4096;
  int S = (fixed + (size_t)N3 * 64 <= ws_size) ? 16 : 1;

  char* p = (char*)d_ws;
  auto alloc = [&](size_t bytes) {
    char* r = p;
    p += (bytes + 255) & ~(size_t)255;
    return r;
  };
  int* cnt_pad = (int*)alloc((size_t)N3 * 4 * S);  // padded counters
  int* rs_all = (int*)alloc((size_t)(N3 + 1) * 4);
  int* part = (int*)alloc(1024 * 4);
  u16* Wtg = (u16*)alloc((size_t)9 * 16384 * 2);
  int* csr_all = (int*)alloc((size_t)nE * 4);
  u16* pos = (u16*)alloc((size_t)nE * 2);
  u16* h_all = (u16*)alloc((size_t)(NU + NI) * D * 2);  // [hu | hi]
  u16* M_all = (u16*)alloc((size_t)N3 * D * 2);         // [Mf | Mc | Mcb]

  hipMemsetAsync(cnt_pad, 0, (size_t)N3 * 4 * S, stream);

  k_convert<<<(NU * D / 8 + 255) / 256, 256, 0, stream>>>(h_user, h_all, NU * D / 8);
  k_convert<<<(NI * D / 8 + 255) / 256, 256, 0, stream>>>(h_item, h_all + (size_t)NU * D,
                                                          NI * D / 8);
  k_convW<<<(9 * 16384 + 255) / 256, 256, 0, stream>>>(W, Wtg, 9 * 16384);

  k_countpos<<<(nE + 255) / 256, 256, 0, stream>>>(f_dst, c_dst, cb_dst, cnt_pad, pos,
                                                   NU, NI, nEf, nEc, nEcb, S);

  int n_part = (N3 + 1023) / 1024;
  k_scanA<<<n_part, 256, 0, stream>>>(cnt_pad, part, N3, S);
  k_scanB<<<1, 1024, 0, stream>>>(part, n_part);
  k_scanC<<<n_part, 256, 0, stream>>>(cnt_pad, part, rs_all, N3, nE, S);

  k_fillpos<<<(nE + 255) / 256, 256, 0, stream>>>(f_src, f_dst, c_src, c_dst,
                                                  cb_src, cb_dst, rs_all, pos,
                                                  csr_all, NU, NI, nEf, nEc, nEcb);

  int nbI = (NI + 127) / 128;
  int nbU = (NU + 127) / 128;
  int agg_blocks = ((N3 + 3) / 4 + 3) / 4;

  for (int l = 0; l < 3; ++l) {
    const u16* Wl = Wtg + (size_t)l * 3 * 16384;
    const float* bl = bb + (size_t)l * 3 * D;

    k_agg3<<<agg_blocks, 256, 0, stream>>>(h_all, csr_all, rs_all, M_all, N3);

    if (l < 2)
      k_gemm2<0><<<nbI + nbU, 256, 0, stream>>>(M_all, Wl, bl, rs_all, h_all,
                                                (float*)d_out, NU, NI, nbI);
    else
      k_gemm2<1><<<nbI + nbU, 256, 0, stream>>>(M_all, Wl, bl, rs_all, h_all,
                                                (float*)d_out, NU, NI, nbI);
  }
}